// Round 18
// baseline (230.025 us; speedup 1.0000x reference)
//
#include <hip/hip_runtime.h>
#include <hip/hip_bf16.h>
#include <stdint.h>

#define M_TOK 32768
#define DIM   1024
#define ODIM  1024
#define KTOT  4096            // NEXP * DIM (Wt row length)
#define NBIN  16              // expert-pair groups (e0*4+e1)
#define MTILES 272            // ceil((32768 + 16*127)/128) rounded to mult of 8
#define PERM_LEN (MTILES * 128)   // 34816
#define GEMM_GRID (8 * 34 * 16)   // 8 xcd * 34 mtiles/xcd * 16 nblk = 4352
#define NT (DIM / 64)         // 16 K-steps

// fused pre-pass block ranges (cvt_x is gone — fused into the GEMM)
#define NB_CVTW 4096
#define NB_HIST 128
#define NB_PRE  (NB_CVTW + NB_HIST)

typedef unsigned short u16;
typedef __bf16 bf16x8 __attribute__((ext_vector_type(8)));
typedef float  f32x4  __attribute__((ext_vector_type(4)));
typedef unsigned int u32x4 __attribute__((ext_vector_type(4)));

__device__ inline u16 f2bf(float f) {
  union { float f; unsigned u; } v; v.f = f;
  unsigned u = v.u;
  unsigned r = u + 0x7FFFu + ((u >> 16) & 1u);
  return (u16)(r >> 16);
}

__device__ inline void async16(const void* g, void* l) {
  __builtin_amdgcn_global_load_lds(
      (const __attribute__((address_space(1))) unsigned int*)g,
      (__attribute__((address_space(3))) unsigned int*)l, 16, 0, 0);
}

// ---- fused pre-pass: [0,4096) cvt_wt | [4096,4224) hist. ctrl pre-zeroed.
__global__ void pre_pass(const float* __restrict__ W, u16* __restrict__ Wt,
                         const int* __restrict__ tki, int* __restrict__ ctrl) {
  __shared__ float t[32][33];
  __shared__ int h[NBIN];
  const int b = blockIdx.x, tid = threadIdx.x;

  if (b < NB_CVTW) {
    // W (E*D, O) fp32 -> Wt (O, E*D) bf16, 32x32 tile transpose
    const int kk0 = (b & 127) * 32, n0 = (b >> 7) * 32;
    const int tx = tid & 31, ty = tid >> 5;   // (32,8)
#pragma unroll
    for (int j = 0; j < 32; j += 8)
      t[ty + j][tx] = W[(size_t)(kk0 + ty + j) * ODIM + n0 + tx];
    __syncthreads();
#pragma unroll
    for (int j = 0; j < 32; j += 8)
      Wt[(size_t)(n0 + ty + j) * KTOT + kk0 + tx] = f2bf(t[tx][ty + j]);
  } else {
    // expert-pair histogram
    const int bb = b - NB_CVTW;
    if (tid < NBIN) h[tid] = 0;
    __syncthreads();
    int tok = bb * 256 + tid;   // 128 blocks x 256 = 32768 tokens
    int e0 = tki[2 * tok] & 3, e1 = tki[2 * tok + 1] & 3;
    atomicAdd(&h[e0 * 4 + e1], 1);
    __syncthreads();
    if (tid < NBIN) atomicAdd(&ctrl[tid], h[tid]);
  }
}

// ---- scatter w/ local plan (offsets from final counts; cursors ctrl[16..31])
__global__ void scatter(const int* __restrict__ tki, const float* __restrict__ ew,
                        int* __restrict__ ctrl,
                        int* __restrict__ perm, float2* __restrict__ wgt2) {
  __shared__ int h[NBIN], gbase[NBIN], cur[NBIN], offs[NBIN];
  int tid = threadIdx.x;
  if (tid < NBIN) { h[tid] = 0; cur[tid] = 0; }
  if (tid == 0) {
    int off = 0;
#pragma unroll
    for (int b = 0; b < NBIN; ++b) {
      offs[b] = off;
      off += (ctrl[b] + 127) & ~127;   // pad each pair-group to 128 rows
    }
  }
  __syncthreads();
  int t = blockIdx.x * 256 + tid;
  int e0 = tki[2 * t] & 3, e1 = tki[2 * t + 1] & 3;
  int bin = e0 * 4 + e1;
  atomicAdd(&h[bin], 1);
  __syncthreads();
  if (tid < NBIN && h[tid] > 0)
    gbase[tid] = offs[tid] + atomicAdd(&ctrl[16 + tid], h[tid]);
  __syncthreads();
  int rank = atomicAdd(&cur[bin], 1);
  int pos = gbase[bin] + rank;
  perm[pos] = t;
  float2 w; w.x = ew[2 * t]; w.y = ew[2 * t + 1];
  wgt2[pos] = w;
}

// ---- fused pair-grouped GEMM with in-kernel A conversion (fp32 x -> bf16):
// out[t] = w0*(x@W_e0+b_e0) + w1*(x@W_e1+b_e1). 128 tok x 64 cols (x2 exp),
// 256 thr = 4 waves (2x2), wave-tile 64x32/expert, acc = 64 regs.
// RACE-FREE full-fence pipeline (round-16's raw-barrier version raced):
//   iter kt: issue A(kt+1)->regs + B(kt+1)->dead Bs dbuf (latency under
//   compute); compute As/Bs[b]; __syncthreads #1 (all reads done, loads
//   landed); cvt+swizzled ds_write As(kt+1); __syncthreads #2 (publish).
// Every LDS read/write pair is separated by a full fence — no raw s_barrier,
// no manual waitcnt. LDS 49.5 KB -> 3 blocks/CU. XCD remap: contiguous runs.
__global__ __launch_bounds__(256, 3) void moe_gemm(
    const float* __restrict__ X,      // [M_TOK][DIM] fp32 (conversion fused)
    const u16* __restrict__ Wt,       // [ODIM][KTOT] bf16
    const int* __restrict__ perm,     // [PERM_LEN] token ids (-1 pad)
    const float2* __restrict__ wgt2,  // [PERM_LEN] (w0,w1)
    const int* __restrict__ tki,      // [M_TOK][2] expert ids
    const float* __restrict__ bias,   // [NEXP][ODIM] fp32
    float* __restrict__ out)          // [M_TOK][ODIM] fp32
{
  __shared__ __align__(16) u16 As[128 * 64];       // 16 KB (single buffer)
  __shared__ __align__(16) u16 Bs[2][2][64 * 64];  // 32 KB (double buffer)
  __shared__ int    rowsS[128];
  __shared__ float2 wgtS[128];

  const int d = blockIdx.x;
  const int slot = d >> 3;                  // 0..543 per XCD
  const int mtile = (d & 7) * (MTILES / 8) + (slot >> 4);
  const int nblk = slot & 15;               // 16 N-blocks of 64 cols
  const int base = mtile * 128;
  const int t0 = perm[base];
  if (t0 < 0) return;                       // fully-padding tile (uniform)
  const int e0 = tki[2 * t0] & 3, e1 = tki[2 * t0 + 1] & 3;

  const int tid = threadIdx.x;
  if (tid < 128) { rowsS[tid] = perm[base + tid]; wgtS[tid] = wgt2[base + tid]; }

  const int wid = tid >> 6, lane = tid & 63;
  const int bcol = nblk * 64;
  const int wr = wid >> 1, wc = wid & 1;    // 2x2 waves; wave-tile 64r x 32c
  const int fcol = bcol + wc * 32;

  f32x4 acc0[4][2], acc1[4][2];
#pragma unroll
  for (int m = 0; m < 4; ++m)
#pragma unroll
    for (int n = 0; n < 2; ++n) {
      acc0[m][n] = (f32x4){0.f, 0.f, 0.f, 0.f};
      acc1[m][n] = (f32x4){0.f, 0.f, 0.f, 0.f};
    }

  const int srow = lane >> 3;                // 0..7
  const int lcol = lane & 7;                 // linear col group (A loads)
  const int scol = (lcol ^ srow) * 8;        // pre-swizzled source col (B)
  const int hi16 = (lane >> 4) * 16;
  const int swz  = (lane & 7) << 4;

  __syncthreads();                           // rowsS/wgtS ready

  // A: fp32 gather pointers (linear cols; swizzle applied on ds_write)
  const float* aptrF[4];
#pragma unroll
  for (int i = 0; i < 4; ++i) {
    int c = wid * 4 + i;                     // 0..15: A rows c*8+srow (0..127)
    int r = rowsS[c * 8 + srow];
    if (r < 0) r = 0;                        // pad row: stage row 0, discard later
    aptrF[i] = X + (size_t)r * DIM + lcol * 8;
  }
  // B: bf16 pointers, pre-swizzled source col
  const u16* b0ptr[2];
  const u16* b1ptr[2];
#pragma unroll
  for (int i = 0; i < 2; ++i) {
    int c = wid * 2 + i;                     // 0..7: B rows c*8+srow (0..63)
    size_t wrow = (size_t)(bcol + c * 8 + srow) * KTOT + scol;
    b0ptr[i] = Wt + wrow + e0 * DIM;
    b1ptr[i] = Wt + wrow + e1 * DIM;
  }
  // A ds_write base: chunk i at +i*1024 B; row srow; swizzled pos (lcol^srow)
  char* awr = (char*)As + (size_t)(wid * 4) * 1024 + srow * 128 + ((lcol ^ srow) << 4);

  float4 aLo[4], aHi[4];
#define A_LOAD(kt) do { _Pragma("unroll")                                   \
    for (int i_ = 0; i_ < 4; ++i_) {                                        \
      const float4* p_ = (const float4*)(aptrF[i_] + (kt) * 64);            \
      aLo[i_] = p_[0]; aHi[i_] = p_[1]; } } while (0)
#define B_STAGE(bb, kt) do { _Pragma("unroll")                              \
    for (int i_ = 0; i_ < 2; ++i_) {                                        \
      async16(b0ptr[i_] + (kt) * 64, &Bs[bb][0][(wid * 2 + i_) * 512]);     \
      async16(b1ptr[i_] + (kt) * 64, &Bs[bb][1][(wid * 2 + i_) * 512]); } } while (0)
#define A_CVT_WRITE() do { _Pragma("unroll")                                \
    for (int i_ = 0; i_ < 4; ++i_) {                                        \
      unsigned w0_, w1_, w2_, w3_;                                          \
      asm volatile("v_cvt_pk_bf16_f32 %0, %1, %2" : "=v"(w0_) : "v"(aLo[i_].x), "v"(aLo[i_].y)); \
      asm volatile("v_cvt_pk_bf16_f32 %0, %1, %2" : "=v"(w1_) : "v"(aLo[i_].z), "v"(aLo[i_].w)); \
      asm volatile("v_cvt_pk_bf16_f32 %0, %1, %2" : "=v"(w2_) : "v"(aHi[i_].x), "v"(aHi[i_].y)); \
      asm volatile("v_cvt_pk_bf16_f32 %0, %1, %2" : "=v"(w3_) : "v"(aHi[i_].z), "v"(aHi[i_].w)); \
      u32x4 v_ = {w0_, w1_, w2_, w3_};                                      \
      *(u32x4*)(awr + i_ * 1024) = v_; } } while (0)

  // prologue: tile 0. A: load->cvt->write (serial, once). B: async16 -> Bs[0].
  A_LOAD(0);
  B_STAGE(0, 0);
  A_CVT_WRITE();
  __syncthreads();                           // B(0) landed, As(0) published

  for (int kt = 0; kt < NT; ++kt) {
    const int b = kt & 1;
    // issue next tile's loads: A->regs (no LDS), B->dead half of dbuf
    if (kt + 1 < NT) {
      A_LOAD(kt + 1);
      B_STAGE(b ^ 1, kt + 1);
    }
    const char* AsB  = (const char*)As;
    const char* Bs0B = (const char*)Bs[b][0];
    const char* Bs1B = (const char*)Bs[b][1];
#pragma unroll
    for (int kk = 0; kk < 2; ++kk) {
      const int cb = (kk * 64 + hi16) ^ swz;
      bf16x8 af[4], bf0[2], bf1[2];
#pragma unroll
      for (int m = 0; m < 4; ++m) {
        int row = wr * 64 + m * 16 + (lane & 15);
        af[m] = *reinterpret_cast<const bf16x8*>(AsB + row * 128 + cb);
      }
#pragma unroll
      for (int n = 0; n < 2; ++n) {
        int row = wc * 32 + n * 16 + (lane & 15);
        bf0[n] = *reinterpret_cast<const bf16x8*>(Bs0B + row * 128 + cb);
        bf1[n] = *reinterpret_cast<const bf16x8*>(Bs1B + row * 128 + cb);
      }
#pragma unroll
      for (int m = 0; m < 4; ++m)
#pragma unroll
        for (int n = 0; n < 2; ++n) {
          acc0[m][n] = __builtin_amdgcn_mfma_f32_16x16x32_bf16(af[m], bf0[n], acc0[m][n], 0, 0, 0);
          acc1[m][n] = __builtin_amdgcn_mfma_f32_16x16x32_bf16(af[m], bf1[n], acc1[m][n], 0, 0, 0);
        }
    }
    // fence #1: all waves' reads of As/Bs[b] complete; vmcnt drained =>
    // A(kt+1) regs + B(kt+1) LDS landed (issued a full compute phase ago).
    __syncthreads();
    if (kt + 1 < NT) A_CVT_WRITE();          // write As(kt+1) — no live readers
    // fence #2: publish As(kt+1) to all waves (lgkm drain + barrier, cheap).
    __syncthreads();
  }
#undef A_LOAD
#undef B_STAGE
#undef A_CVT_WRITE

  // epilogue: single store, both experts combined
  float bb0[2], bb1[2];
#pragma unroll
  for (int n = 0; n < 2; ++n) {
    int col = fcol + n * 16 + (lane & 15);
    bb0[n] = bias[e0 * ODIM + col];
    bb1[n] = bias[e1 * ODIM + col];
  }

#pragma unroll
  for (int m = 0; m < 4; ++m) {
#pragma unroll
    for (int r = 0; r < 4; ++r) {
      int rl = wr * 64 + m * 16 + (lane >> 4) * 4 + r;
      int t = rowsS[rl];
      if (t < 0) continue;
      float2 w = wgtS[rl];
      size_t o = (size_t)t * ODIM + fcol + (lane & 15);
#pragma unroll
      for (int n = 0; n < 2; ++n)
        out[o + n * 16] = w.x * (acc0[m][n][r] + bb0[n]) + w.y * (acc1[m][n][r] + bb1[n]);
    }
  }
}

extern "C" void kernel_launch(void* const* d_in, const int* in_sizes, int n_in,
                              void* d_out, int out_size, void* d_ws, size_t ws_size,
                              hipStream_t stream) {
  const float* x    = (const float*)d_in[0];
  const float* ew   = (const float*)d_in[1];
  const int*   tki  = (const int*)d_in[2];
  const float* W    = (const float*)d_in[3];
  const float* bias = (const float*)d_in[4];
  float* out = (float*)d_out;

  char* ws = (char*)d_ws;
  u16*    wt   = (u16*)ws;                               //  8,388,608 B
  int*    ctrl = (int*)(ws + 8388608);                   //       128 B
  int*    perm = (int*)(ws + 8388864);                   //   139,264 B
  float2* wgt2 = (float2*)(ws + 8528128);                //   278,528 B -> end 8,806,656

  hipMemsetAsync(ctrl, 0, 128, stream);                       // counts + cursors
  hipMemsetAsync(perm, 0xFF, PERM_LEN * sizeof(int), stream); // perm = -1
  pre_pass<<<NB_PRE, 256, 0, stream>>>(W, wt, tki, ctrl);
  scatter<<<128, 256, 0, stream>>>(tki, ew, ctrl, perm, wgt2);
  moe_gemm<<<GEMM_GRID, 256, 0, stream>>>(x, wt, perm, wgt2, tki, bias, out);
}

// Round 19
// 190.311 us; speedup vs baseline: 1.2087x; 1.2087x over previous
//
#include <hip/hip_runtime.h>
#include <hip/hip_bf16.h>
#include <stdint.h>

#define M_TOK 32768
#define DIM   1024
#define ODIM  1024
#define NEXP  4
#define KTOT  4096            // NEXP * DIM (Wt row length)
#define NBIN  16              // expert-pair groups (e0*4+e1)
#define MTILES 272            // ceil((32768 + 16*127)/128) rounded to mult of 8
#define PERM_LEN (MTILES * 128)   // 34816
#define GEMM_GRID (8 * 34 * 16)   // 8 xcd * 34 mtiles/xcd * 16 nblk = 4352

// fused pre-pass block ranges
#define NB_CVTX 4096
#define NB_CVTW 4096
#define NB_HIST 128
#define NB_PRE  (NB_CVTX + NB_CVTW + NB_HIST)

typedef unsigned short u16;
typedef __bf16 bf16x8 __attribute__((ext_vector_type(8)));
typedef float  f32x4  __attribute__((ext_vector_type(4)));

__device__ inline u16 f2bf(float f) {
  union { float f; unsigned u; } v; v.f = f;
  unsigned u = v.u;
  unsigned r = u + 0x7FFFu + ((u >> 16) & 1u);
  return (u16)(r >> 16);
}

__device__ inline unsigned pack2(float lo, float hi) {
  return (unsigned)f2bf(lo) | ((unsigned)f2bf(hi) << 16);
}

__device__ inline void async16(const void* g, void* l) {
  __builtin_amdgcn_global_load_lds(
      (const __attribute__((address_space(1))) unsigned int*)g,
      (__attribute__((address_space(3))) unsigned int*)l, 16, 0, 0);
}

// ---- fused pre-pass: [0,4096) cvt_x | [4096,8192) cvt_wt | [8192,8320) hist
// ctrl must be pre-zeroed (hipMemsetAsync).
__global__ void pre_pass(const float* __restrict__ x, uint4* __restrict__ xb,
                         const float* __restrict__ W, u16* __restrict__ Wt,
                         const int* __restrict__ tki, int* __restrict__ ctrl) {
  __shared__ float t[32][33];
  __shared__ int h[NBIN];
  const int b = blockIdx.x, tid = threadIdx.x;

  if (b < NB_CVTX) {
    // x fp32 -> bf16, 8 elems/thread/iter
    const float4* xv = (const float4*)x;
    const int n8 = M_TOK * DIM / 8;
    for (int i = b * 256 + tid; i < n8; i += NB_CVTX * 256) {
      float4 a = xv[2 * i];
      float4 c = xv[2 * i + 1];
      uint4 o;
      o.x = pack2(a.x, a.y); o.y = pack2(a.z, a.w);
      o.z = pack2(c.x, c.y); o.w = pack2(c.z, c.w);
      xb[i] = o;
    }
  } else if (b < NB_CVTX + NB_CVTW) {
    // W (E*D, O) fp32 -> Wt (O, E*D) bf16, 32x32 tile transpose
    const int bb = b - NB_CVTX;
    const int kk0 = (bb & 127) * 32, n0 = (bb >> 7) * 32;
    const int tx = tid & 31, ty = tid >> 5;   // (32,8)
#pragma unroll
    for (int j = 0; j < 32; j += 8)
      t[ty + j][tx] = W[(size_t)(kk0 + ty + j) * ODIM + n0 + tx];
    __syncthreads();
#pragma unroll
    for (int j = 0; j < 32; j += 8)
      Wt[(size_t)(n0 + ty + j) * KTOT + kk0 + tx] = f2bf(t[tx][ty + j]);
  } else {
    // expert-pair histogram
    const int bb = b - NB_CVTX - NB_CVTW;
    if (tid < NBIN) h[tid] = 0;
    __syncthreads();
    int tok = bb * 256 + tid;   // 128 blocks x 256 = 32768 tokens
    int e0 = tki[2 * tok] & 3, e1 = tki[2 * tok + 1] & 3;
    atomicAdd(&h[e0 * 4 + e1], 1);
    __syncthreads();
    if (tid < NBIN) atomicAdd(&ctrl[tid], h[tid]);
  }
}

// ---- scatter w/ local plan: offsets computed per-block from final counts;
// global cursors at ctrl[16..31] (pre-zeroed by memset).
__global__ void scatter(const int* __restrict__ tki, const float* __restrict__ ew,
                        int* __restrict__ ctrl,
                        int* __restrict__ perm, float2* __restrict__ wgt2) {
  __shared__ int h[NBIN], gbase[NBIN], cur[NBIN], offs[NBIN];
  int tid = threadIdx.x;
  if (tid < NBIN) { h[tid] = 0; cur[tid] = 0; }
  if (tid == 0) {
    int off = 0;
#pragma unroll
    for (int b = 0; b < NBIN; ++b) {
      offs[b] = off;
      off += (ctrl[b] + 127) & ~127;   // pad each pair-group to 128 rows
    }
  }
  __syncthreads();
  int t = blockIdx.x * 256 + tid;
  int e0 = tki[2 * t] & 3, e1 = tki[2 * t + 1] & 3;
  int bin = e0 * 4 + e1;
  atomicAdd(&h[bin], 1);
  __syncthreads();
  if (tid < NBIN && h[tid] > 0)
    gbase[tid] = offs[tid] + atomicAdd(&ctrl[16 + tid], h[tid]);
  __syncthreads();
  int rank = atomicAdd(&cur[bin], 1);
  int pos = gbase[bin] + rank;
  perm[pos] = t;
  float2 w; w.x = ew[2 * t]; w.y = ew[2 * t + 1];
  wgt2[pos] = w;
}

// ---- fused single-pass grouped GEMM: out[t] = w0*(x@W_e0+b_e0) + w1*(x@W_e1+b_e1)
// (verified round-13/15 kernel). Tokens grouped by expert PAIR.
// 128 tok x 64 N-cols per block, 256 thr = 4 waves (2x2), wave-tile 64x32
// per expert, acc0+acc1 = 64 regs. 2-barrier template: 8 async16 : 32 MFMA
// per K-step, XOR swizzle. XCD remap: each XCD owns a contiguous run of 34
// mtiles (bin-sorted perm => concurrent mtiles share one 4MB W-panel in L2);
// 16 nblk of one mtile concurrent on the XCD => A-panel reuse.
__global__ __launch_bounds__(256, 4) void moe_gemm(
    const u16* __restrict__ Xb,       // [M_TOK][DIM] bf16
    const u16* __restrict__ Wt,       // [ODIM][KTOT] bf16
    const int* __restrict__ perm,     // [PERM_LEN] token ids (-1 pad)
    const float2* __restrict__ wgt2,  // [PERM_LEN] (w0,w1)
    const int* __restrict__ tki,      // [M_TOK][2] expert ids
    const float* __restrict__ bias,   // [NEXP][ODIM] fp32
    float* __restrict__ out)          // [M_TOK][ODIM] fp32
{
  __shared__ __align__(16) u16 As [128 * 64];   // 16 KB
  __shared__ __align__(16) u16 Bs0[64 * 64];    // 8 KB
  __shared__ __align__(16) u16 Bs1[64 * 64];    // 8 KB
  __shared__ int    rowsS[128];
  __shared__ float2 wgtS[128];

  const int d = blockIdx.x;
  const int slot = d >> 3;                  // 0..543 per XCD
  const int mtile = (d & 7) * (MTILES / 8) + (slot >> 4);
  const int nblk = slot & 15;               // 16 N-blocks of 64 cols
  const int base = mtile * 128;
  const int t0 = perm[base];
  if (t0 < 0) return;                       // fully-padding tile (uniform)
  const int e0 = tki[2 * t0] & 3, e1 = tki[2 * t0 + 1] & 3;

  const int tid = threadIdx.x;
  if (tid < 128) { rowsS[tid] = perm[base + tid]; wgtS[tid] = wgt2[base + tid]; }

  const int wid = tid >> 6, lane = tid & 63;
  const int bcol = nblk * 64;
  const int wr = wid >> 1, wc = wid & 1;    // 2x2 waves; wave-tile 64 rows x 32 cols
  const int fcol = bcol + wc * 32;

  f32x4 acc0[4][2], acc1[4][2];
#pragma unroll
  for (int m = 0; m < 4; ++m)
#pragma unroll
    for (int n = 0; n < 2; ++n) {
      acc0[m][n] = (f32x4){0.f, 0.f, 0.f, 0.f};
      acc1[m][n] = (f32x4){0.f, 0.f, 0.f, 0.f};
    }

  const int srow = lane >> 3;                // 0..7
  const int scol = ((lane & 7) ^ srow) * 8;  // pre-swizzled source col
  const int hi16 = (lane >> 4) * 16;
  const int swz  = (lane & 7) << 4;
  const char* AsB  = (const char*)As;
  const char* Bs0B = (const char*)Bs0;
  const char* Bs1B = (const char*)Bs1;

  __syncthreads();                           // rowsS/wgtS ready

  // staging base pointers: 4 A-chunks + 2 B0-chunks + 2 B1-chunks per wave
  const u16* aptr[4];
  const u16* b0ptr[2];
  const u16* b1ptr[2];
#pragma unroll
  for (int i = 0; i < 4; ++i) {
    int c = wid * 4 + i;                     // 0..15: A rows c*8+srow (0..127)
    int r = rowsS[c * 8 + srow];
    if (r < 0) r = 0;                        // pad row: stage row 0, discard later
    aptr[i] = Xb + (size_t)r * DIM + scol;
  }
#pragma unroll
  for (int i = 0; i < 2; ++i) {
    int c = wid * 2 + i;                     // 0..7: B rows c*8+srow (0..63)
    size_t wrow = (size_t)(bcol + c * 8 + srow) * KTOT + scol;
    b0ptr[i] = Wt + wrow + e0 * DIM;
    b1ptr[i] = Wt + wrow + e1 * DIM;
  }

  for (int kt = 0; kt < DIM / 64; ++kt) {    // 16 K-steps
    __syncthreads();
#pragma unroll
    for (int i = 0; i < 4; ++i)
      async16(aptr[i] + kt * 64, &As[(wid * 4 + i) * 512]);
#pragma unroll
    for (int i = 0; i < 2; ++i) {
      async16(b0ptr[i] + kt * 64, &Bs0[(wid * 2 + i) * 512]);
      async16(b1ptr[i] + kt * 64, &Bs1[(wid * 2 + i) * 512]);
    }
    __syncthreads();
#pragma unroll
    for (int kk = 0; kk < 2; ++kk) {
      const int cb = (kk * 64 + hi16) ^ swz;
      bf16x8 af[4], bf0[2], bf1[2];
#pragma unroll
      for (int m = 0; m < 4; ++m) {
        int row = wr * 64 + m * 16 + (lane & 15);
        af[m] = *reinterpret_cast<const bf16x8*>(AsB + row * 128 + cb);
      }
#pragma unroll
      for (int n = 0; n < 2; ++n) {
        int row = wc * 32 + n * 16 + (lane & 15);
        bf0[n] = *reinterpret_cast<const bf16x8*>(Bs0B + row * 128 + cb);
        bf1[n] = *reinterpret_cast<const bf16x8*>(Bs1B + row * 128 + cb);
      }
#pragma unroll
      for (int m = 0; m < 4; ++m)
#pragma unroll
        for (int n = 0; n < 2; ++n) {
          acc0[m][n] = __builtin_amdgcn_mfma_f32_16x16x32_bf16(af[m], bf0[n], acc0[m][n], 0, 0, 0);
          acc1[m][n] = __builtin_amdgcn_mfma_f32_16x16x32_bf16(af[m], bf1[n], acc1[m][n], 0, 0, 0);
        }
    }
  }

  // epilogue: single store, both experts combined
  float bb0[2], bb1[2];
#pragma unroll
  for (int n = 0; n < 2; ++n) {
    int col = fcol + n * 16 + (lane & 15);
    bb0[n] = bias[e0 * ODIM + col];
    bb1[n] = bias[e1 * ODIM + col];
  }

#pragma unroll
  for (int m = 0; m < 4; ++m) {
#pragma unroll
    for (int r = 0; r < 4; ++r) {
      int rl = wr * 64 + m * 16 + (lane >> 4) * 4 + r;
      int t = rowsS[rl];
      if (t < 0) continue;
      float2 w = wgtS[rl];
      size_t o = (size_t)t * ODIM + fcol + (lane & 15);
#pragma unroll
      for (int n = 0; n < 2; ++n)
        out[o + n * 16] = w.x * (acc0[m][n][r] + bb0[n]) + w.y * (acc1[m][n][r] + bb1[n]);
    }
  }
}

extern "C" void kernel_launch(void* const* d_in, const int* in_sizes, int n_in,
                              void* d_out, int out_size, void* d_ws, size_t ws_size,
                              hipStream_t stream) {
  const float* x    = (const float*)d_in[0];
  const float* ew   = (const float*)d_in[1];
  const int*   tki  = (const int*)d_in[2];
  const float* W    = (const float*)d_in[3];
  const float* bias = (const float*)d_in[4];
  float* out = (float*)d_out;

  char* ws = (char*)d_ws;
  u16*    xb   = (u16*)ws;                               // 67,108,864 B
  u16*    wt   = (u16*)(ws + 67108864);                  //  8,388,608 B
  int*    ctrl = (int*)(ws + 75497472);                  //       128 B
  int*    perm = (int*)(ws + 75497728);                  //   139,264 B
  float2* wgt2 = (float2*)(ws + 75636992);               //   278,528 B -> end 75,915,520

  hipMemsetAsync(ctrl, 0, 128, stream);                     // counts + cursors
  hipMemsetAsync(perm, 0xFF, PERM_LEN * sizeof(int), stream); // perm = -1
  pre_pass<<<NB_PRE, 256, 0, stream>>>(x, (uint4*)xb, W, wt, tki, ctrl);
  scatter<<<128, 256, 0, stream>>>(tki, ew, ctrl, perm, wgt2);
  moe_gemm<<<GEMM_GRID, 256, 0, stream>>>(xb, wt, perm, wgt2, tki, bias, out);
}